// Round 1
// baseline (997.070 us; speedup 1.0000x reference)
//
#include <hip/hip_runtime.h>
#include <math.h>

// ---------------------------------------------------------------------------
// GATv2 x2 layers.  Strategy:
//   - Build CSR-by-dst once (hist -> scan -> atomic scatter), shared by both
//     layers (same graph).  Self loops appended with mean(edge_weight).
//   - 4 small fp32 GEMMs (128x128 weights) with x-tile in LDS.
//   - Aggregation: one wave (64 lanes) per node, online softmax, each lane
//     owns channels {l, l+64} (head = hc/32).  No float atomics anywhere.
// ---------------------------------------------------------------------------

__global__ void sum_ew_kernel(const float* __restrict__ ew, float* __restrict__ sumbuf, int E) {
    float s = 0.f;
    for (int i = blockIdx.x * blockDim.x + threadIdx.x; i < E; i += gridDim.x * blockDim.x)
        s += ew[i];
#pragma unroll
    for (int off = 1; off <= 32; off <<= 1)
        s += __shfl_xor(s, off, 64);
    if ((threadIdx.x & 63) == 0)
        atomicAdd(sumbuf, s);
}

__global__ void hist_kernel(const int* __restrict__ dst, int* __restrict__ cnt, int E) {
    int i = blockIdx.x * blockDim.x + threadIdx.x;
    if (i < E) atomicAdd(&cnt[dst[i]], 1);
}

// exclusive scan of (cnt[i]+1), 3-kernel hierarchy; nb <= 256 blocks of 256
__global__ void scan1_kernel(const int* __restrict__ cnt, int* __restrict__ rowp,
                             int* __restrict__ bsum, int N) {
    __shared__ int sh[256];
    int i = blockIdx.x * 256 + threadIdx.x;
    int v = (i < N) ? (cnt[i] + 1) : 0;
    sh[threadIdx.x] = v;
    __syncthreads();
    for (int off = 1; off < 256; off <<= 1) {
        int y = 0;
        if ((int)threadIdx.x >= off) y = sh[threadIdx.x - off];
        __syncthreads();
        sh[threadIdx.x] += y;
        __syncthreads();
    }
    int incl = sh[threadIdx.x];
    if (i < N) rowp[i] = incl - v;               // block-local exclusive
    if (threadIdx.x == 255) bsum[blockIdx.x] = incl;
}

__global__ void scan2_kernel(int* __restrict__ bsum, int nb) {
    __shared__ int sh[256];
    int v = ((int)threadIdx.x < nb) ? bsum[threadIdx.x] : 0;
    sh[threadIdx.x] = v;
    __syncthreads();
    for (int off = 1; off < 256; off <<= 1) {
        int y = 0;
        if ((int)threadIdx.x >= off) y = sh[threadIdx.x - off];
        __syncthreads();
        sh[threadIdx.x] += y;
        __syncthreads();
    }
    int incl = sh[threadIdx.x];
    if ((int)threadIdx.x < nb) bsum[threadIdx.x] = incl - v;  // exclusive block offsets
}

__global__ void scan3_kernel(int* __restrict__ rowp, const int* __restrict__ bsum,
                             int* __restrict__ cursor, int N, int E) {
    int i = blockIdx.x * 256 + threadIdx.x;
    if (i < N) {
        int rp = rowp[i] + bsum[blockIdx.x];
        rowp[i] = rp;
        cursor[i] = rp;
    }
    if (i == 0) rowp[N] = E + N;
}

__global__ void scatter_kernel(const int* __restrict__ src, const int* __restrict__ dst,
                               const float* __restrict__ ew, const float* __restrict__ sumbuf,
                               int* __restrict__ cursor, int* __restrict__ csrc,
                               float* __restrict__ cwt, int E, int N) {
    int i = blockIdx.x * blockDim.x + threadIdx.x;
    if (i < E) {
        int d = dst[i];
        int pos = atomicAdd(&cursor[d], 1);
        csrc[pos] = src[i];
        cwt[pos] = ew[i];
    } else if (i < E + N) {
        int n = i - E;
        int pos = atomicAdd(&cursor[n], 1);
        csrc[pos] = n;
        cwt[pos] = sumbuf[0] * (1.0f / (float)E);   // mean edge weight
    }
}

// Y_a = X @ Wa, Y_b = X @ Wb   (X: N x 128, W: 128 x 128, fp32)
// block = 256 threads; 64 rows/block; thread t -> column (t&127) of Wa (t<128) or Wb.
__global__ __launch_bounds__(256) void gemm_dual_kernel(
    const float* __restrict__ X, const float* __restrict__ Wa, const float* __restrict__ Wb,
    float* __restrict__ Ya, float* __restrict__ Yb, int N) {
    __shared__ float xt[64 * 128];
    int rb = blockIdx.x * 64;
    for (int t = threadIdx.x; t < 2048; t += 256) {   // 2048 float4 = 64 rows x 32
        int r = t >> 5;
        int c4 = t & 31;
        int row = rb + r;
        float4 v = make_float4(0.f, 0.f, 0.f, 0.f);
        if (row < N) v = ((const float4*)X)[(size_t)row * 32 + c4];
        ((float4*)xt)[t] = v;
    }
    __syncthreads();
    const float* W = (threadIdx.x < 128) ? Wa : Wb;
    float* Y = (threadIdx.x < 128) ? Ya : Yb;
    int col = threadIdx.x & 127;
    float acc[64];
#pragma unroll
    for (int r = 0; r < 64; r++) acc[r] = 0.f;
    for (int k = 0; k < 128; k += 4) {
        float w0 = W[(k + 0) * 128 + col];
        float w1 = W[(k + 1) * 128 + col];
        float w2 = W[(k + 2) * 128 + col];
        float w3 = W[(k + 3) * 128 + col];
        int k4 = k >> 2;
#pragma unroll
        for (int r = 0; r < 64; r++) {
            float4 xv = ((const float4*)xt)[r * 32 + k4];
            acc[r] = fmaf(xv.x, w0, fmaf(xv.y, w1, fmaf(xv.z, w2, fmaf(xv.w, w3, acc[r]))));
        }
    }
    int rmax = N - rb; if (rmax > 64) rmax = 64;
    for (int r = 0; r < rmax; r++)
        Y[(size_t)(rb + r) * 128 + col] = acc[r];
}

// One wave per node. lane owns channels hc0=lane, hc1=lane+64 (head = hc>>5).
// mode 0: layer1 -> out[n,128] = elu(res + b)    mode 1: layer2 -> out[n,32] = mean_h + b
__global__ __launch_bounds__(256) void agg_kernel(
    const float* __restrict__ xl, const float* __restrict__ xr,
    const int* __restrict__ rowp, const int* __restrict__ csrc, const float* __restrict__ cwt,
    const float* __restrict__ We, const float* __restrict__ att, const float* __restrict__ bias,
    float* __restrict__ out, int N, int mode) {
    int wid = threadIdx.x >> 6;
    int lane = threadIdx.x & 63;
    int n = blockIdx.x * 4 + wid;
    if (n >= N) return;
    int hc0 = lane, hc1 = lane + 64;
    float we0 = We[hc0], we1 = We[hc1];
    float at0 = att[hc0], at1 = att[hc1];
    float xr0 = xr[(size_t)n * 128 + hc0];
    float xr1 = xr[(size_t)n * 128 + hc1];
    float m0 = -INFINITY, m1 = -INFINITY;
    float l0 = 0.f, l1 = 0.f, a0 = 0.f, a1 = 0.f;
    int e0 = rowp[n], e1 = rowp[n + 1];
    for (int e = e0; e < e1; ++e) {
        int s = csrc[e];
        float w = cwt[e];
        float x0 = xl[(size_t)s * 128 + hc0];
        float x1 = xl[(size_t)s * 128 + hc1];
        float z0 = x0 + xr0 + w * we0; z0 = (z0 > 0.f) ? z0 : 0.2f * z0;
        float z1 = x1 + xr1 + w * we1; z1 = (z1 > 0.f) ? z1 : 0.2f * z1;
        float p0 = z0 * at0, p1 = z1 * at1;
#pragma unroll
        for (int off = 1; off < 32; off <<= 1) {   // reduce within 32-lane head group
            p0 += __shfl_xor(p0, off, 64);
            p1 += __shfl_xor(p1, off, 64);
        }
        // online softmax (per head, all 32 lanes of a group hold identical logit)
        float nm0 = fmaxf(m0, p0);
        float sc0 = __expf(m0 - nm0);
        float q0 = __expf(p0 - nm0);
        l0 = l0 * sc0 + q0;
        a0 = a0 * sc0 + q0 * x0;
        m0 = nm0;
        float nm1 = fmaxf(m1, p1);
        float sc1 = __expf(m1 - nm1);
        float q1 = __expf(p1 - nm1);
        l1 = l1 * sc1 + q1;
        a1 = a1 * sc1 + q1 * x1;
        m1 = nm1;
    }
    float r0 = a0 / (l0 + 1e-16f);
    float r1 = a1 / (l1 + 1e-16f);
    if (mode == 0) {
        float v0 = r0 + bias[hc0]; v0 = (v0 > 0.f) ? v0 : (__expf(v0) - 1.f);  // ELU
        float v1 = r1 + bias[hc1]; v1 = (v1 > 0.f) ? v1 : (__expf(v1) - 1.f);
        out[(size_t)n * 128 + hc0] = v0;
        out[(size_t)n * 128 + hc1] = v1;
    } else {
        float t = r0 + r1;                 // heads (g, g+2) at channel c=lane&31
        t += __shfl_xor(t, 32, 64);        // + heads from partner half-wave
        if (lane < 32)
            out[(size_t)n * 32 + lane] = 0.25f * t + bias[lane];
    }
}

extern "C" void kernel_launch(void* const* d_in, const int* in_sizes, int n_in,
                              void* d_out, int out_size, void* d_ws, size_t ws_size,
                              hipStream_t stream) {
    const float* x    = (const float*)d_in[0];
    const int*  eidx  = (const int*)d_in[1];
    const float* ew   = (const float*)d_in[2];
    const float* Wl1  = (const float*)d_in[3];
    const float* Wr1  = (const float*)d_in[4];
    const float* We1  = (const float*)d_in[5];
    const float* att1 = (const float*)d_in[6];
    const float* b1   = (const float*)d_in[7];
    const float* Wl2  = (const float*)d_in[8];
    const float* Wr2  = (const float*)d_in[9];
    const float* We2  = (const float*)d_in[10];
    const float* att2 = (const float*)d_in[11];
    const float* b2   = (const float*)d_in[12];

    const int N = in_sizes[0] / 128;
    const int E = in_sizes[1] / 2;
    const int* src = eidx;
    const int* dst = eidx + E;

    char* p = (char*)d_ws;
    auto alloc = [&](size_t bytes) -> void* {
        void* r = (void*)p;
        p += (bytes + 255) & ~(size_t)255;
        return r;
    };
    float* xl     = (float*)alloc((size_t)N * 128 * sizeof(float));
    float* xr     = (float*)alloc((size_t)N * 128 * sizeof(float));
    float* h1     = (float*)alloc((size_t)N * 128 * sizeof(float));
    int*   csrc   = (int*)alloc((size_t)(E + N) * sizeof(int));
    float* cwt    = (float*)alloc((size_t)(E + N) * sizeof(float));
    int*   rowp   = (int*)alloc((size_t)(N + 1) * sizeof(int));
    int*   cursor = (int*)alloc((size_t)N * sizeof(int));
    int*   cnt    = (int*)alloc((size_t)(N + 8) * sizeof(int));
    float* sumbuf = (float*)(cnt + N);
    int*   bsum   = (int*)alloc(256 * sizeof(int));

    // zero cnt + sumbuf
    hipMemsetAsync(cnt, 0, (size_t)(N + 8) * sizeof(int), stream);

    sum_ew_kernel<<<512, 256, 0, stream>>>(ew, sumbuf, E);
    hist_kernel<<<(E + 255) / 256, 256, 0, stream>>>(dst, cnt, E);

    int nb = (N + 255) / 256;  // 196 for N=50000, must be <= 256
    scan1_kernel<<<nb, 256, 0, stream>>>(cnt, rowp, bsum, N);
    scan2_kernel<<<1, 256, 0, stream>>>(bsum, nb);
    scan3_kernel<<<nb, 256, 0, stream>>>(rowp, bsum, cursor, N, E);

    scatter_kernel<<<(E + N + 255) / 256, 256, 0, stream>>>(src, dst, ew, sumbuf,
                                                            cursor, csrc, cwt, E, N);

    // Layer 1
    gemm_dual_kernel<<<(N + 63) / 64, 256, 0, stream>>>(x, Wl1, Wr1, xl, xr, N);
    agg_kernel<<<(N + 3) / 4, 256, 0, stream>>>(xl, xr, rowp, csrc, cwt,
                                                We1, att1, b1, h1, N, 0);
    // Layer 2
    gemm_dual_kernel<<<(N + 63) / 64, 256, 0, stream>>>(h1, Wl2, Wr2, xl, xr, N);
    agg_kernel<<<(N + 3) / 4, 256, 0, stream>>>(xl, xr, rowp, csrc, cwt,
                                                We2, att2, b2, (float*)d_out, N, 1);
}

// Round 2
// 879.418 us; speedup vs baseline: 1.1338x; 1.1338x over previous
//
#include <hip/hip_runtime.h>
#include <math.h>

// ---------------------------------------------------------------------------
// GATv2 x2 layers.
//   - CSR-by-dst built once (hist -> scan -> atomic scatter), shared by both
//     layers.  Self loops appended with mean(edge_weight).
//   - 2 dual fp32 GEMMs, 8x8 register tiling, A transposed in LDS, W from L2.
//   - Aggregation: one wave per node; fixed-max softmax (exp(p), no online
//     rescale -- identical ratios, logits bounded); att pre-scaled by log2e;
//     scalarized edge metadata (s_load); butterfly reduce on LDS pipe.
// ---------------------------------------------------------------------------

__global__ void sum_ew_kernel(const float* __restrict__ ew, float* __restrict__ sumbuf, int E) {
    float s = 0.f;
    for (int i = blockIdx.x * blockDim.x + threadIdx.x; i < E; i += gridDim.x * blockDim.x)
        s += ew[i];
#pragma unroll
    for (int off = 1; off <= 32; off <<= 1)
        s += __shfl_xor(s, off, 64);
    if ((threadIdx.x & 63) == 0)
        atomicAdd(sumbuf, s);
}

__global__ void hist_kernel(const int* __restrict__ dst, int* __restrict__ cnt, int E) {
    int i = blockIdx.x * blockDim.x + threadIdx.x;
    if (i < E) atomicAdd(&cnt[dst[i]], 1);
}

__global__ void scan1_kernel(const int* __restrict__ cnt, int* __restrict__ rowp,
                             int* __restrict__ bsum, int N) {
    __shared__ int sh[256];
    int i = blockIdx.x * 256 + threadIdx.x;
    int v = (i < N) ? (cnt[i] + 1) : 0;
    sh[threadIdx.x] = v;
    __syncthreads();
    for (int off = 1; off < 256; off <<= 1) {
        int y = 0;
        if ((int)threadIdx.x >= off) y = sh[threadIdx.x - off];
        __syncthreads();
        sh[threadIdx.x] += y;
        __syncthreads();
    }
    int incl = sh[threadIdx.x];
    if (i < N) rowp[i] = incl - v;
    if (threadIdx.x == 255) bsum[blockIdx.x] = incl;
}

__global__ void scan2_kernel(int* __restrict__ bsum, int nb) {
    __shared__ int sh[256];
    int v = ((int)threadIdx.x < nb) ? bsum[threadIdx.x] : 0;
    sh[threadIdx.x] = v;
    __syncthreads();
    for (int off = 1; off < 256; off <<= 1) {
        int y = 0;
        if ((int)threadIdx.x >= off) y = sh[threadIdx.x - off];
        __syncthreads();
        sh[threadIdx.x] += y;
        __syncthreads();
    }
    int incl = sh[threadIdx.x];
    if ((int)threadIdx.x < nb) bsum[threadIdx.x] = incl - v;
}

__global__ void scan3_kernel(int* __restrict__ rowp, const int* __restrict__ bsum,
                             int* __restrict__ cursor, int N, int E) {
    int i = blockIdx.x * 256 + threadIdx.x;
    if (i < N) {
        int rp = rowp[i] + bsum[blockIdx.x];
        rowp[i] = rp;
        cursor[i] = rp;
    }
    if (i == 0) rowp[N] = E + N;
}

__global__ void scatter_kernel(const int* __restrict__ src, const int* __restrict__ dst,
                               const float* __restrict__ ew, const float* __restrict__ sumbuf,
                               int* __restrict__ cursor, int* __restrict__ csrc,
                               float* __restrict__ cwt, int E, int N) {
    int i = blockIdx.x * blockDim.x + threadIdx.x;
    if (i < E) {
        int d = dst[i];
        int pos = atomicAdd(&cursor[d], 1);
        csrc[pos] = src[i];
        cwt[pos] = ew[i];
    } else if (i < E + N) {
        int n = i - E;
        int pos = atomicAdd(&cursor[n], 1);
        csrc[pos] = n;
        cwt[pos] = sumbuf[0] * (1.0f / (float)E);
    }
}

// Ya = X @ Wa, Yb = X @ Wb  (X: N x 128, W: 128 x 128 fp32).
// Block: 256 threads, 64 rows x (128+128) cols. Thread: 8 rows x (4+4) cols.
// A chunk (32 k) transposed in LDS (pad 68 -> 16B-aligned, conflict-light);
// W read directly from global (L2-resident broadcast).
__global__ __launch_bounds__(256) void gemm_dual2_kernel(
    const float* __restrict__ X, const float* __restrict__ Wa, const float* __restrict__ Wb,
    float* __restrict__ Ya, float* __restrict__ Yb, int N) {
    __shared__ float At[32][68];   // [k][row]
    const int tid = threadIdx.x;
    const int rb = blockIdx.x * 64;
    const int tx = tid & 31;       // col group: cols tx*4 in each of Wa, Wb
    const int ty = tid >> 5;       // row group: rows ty*8 .. ty*8+7

    float acc[8][8];
#pragma unroll
    for (int r = 0; r < 8; r++)
#pragma unroll
        for (int c = 0; c < 8; c++) acc[r][c] = 0.f;

    for (int k0 = 0; k0 < 128; k0 += 32) {
        __syncthreads();
        for (int i = tid; i < 512; i += 256) {       // 512 float4 = 64 rows x 8
            int row = i >> 3;
            int kq = i & 7;
            float4 v = make_float4(0.f, 0.f, 0.f, 0.f);
            if (rb + row < N)
                v = ((const float4*)X)[(size_t)(rb + row) * 32 + (k0 >> 2) + kq];
            At[kq * 4 + 0][row] = v.x;
            At[kq * 4 + 1][row] = v.y;
            At[kq * 4 + 2][row] = v.z;
            At[kq * 4 + 3][row] = v.w;
        }
        __syncthreads();
#pragma unroll
        for (int k = 0; k < 32; k++) {
            float4 a0 = *(const float4*)&At[k][ty * 8];
            float4 a1 = *(const float4*)&At[k][ty * 8 + 4];
            float4 b0 = ((const float4*)(Wa + (size_t)(k0 + k) * 128))[tx];
            float4 b1 = ((const float4*)(Wb + (size_t)(k0 + k) * 128))[tx];
            float ar[8] = {a0.x, a0.y, a0.z, a0.w, a1.x, a1.y, a1.z, a1.w};
            float bc[8] = {b0.x, b0.y, b0.z, b0.w, b1.x, b1.y, b1.z, b1.w};
#pragma unroll
            for (int r = 0; r < 8; r++)
#pragma unroll
                for (int c = 0; c < 8; c++)
                    acc[r][c] = fmaf(ar[r], bc[c], acc[r][c]);
        }
    }

#pragma unroll
    for (int r = 0; r < 8; r++) {
        int row = rb + ty * 8 + r;
        if (row < N) {
            ((float4*)Ya)[(size_t)row * 32 + tx] =
                make_float4(acc[r][0], acc[r][1], acc[r][2], acc[r][3]);
            ((float4*)Yb)[(size_t)row * 32 + tx] =
                make_float4(acc[r][4], acc[r][5], acc[r][6], acc[r][7]);
        }
    }
}

// One wave per node. lane owns channels hc0=lane, hc1=lane+64 (head = hc>>5).
// Fixed-max softmax: q = 2^(p * log2e * att-prescaled); exact same ratios as
// the reference's max-subtracted form (logits bounded, no overflow).
// mode 0: out[n,128] = elu(res + b)    mode 1: out[n,32] = mean_h(res) + b
__global__ __launch_bounds__(256) void agg_kernel(
    const float* __restrict__ xl, const float* __restrict__ xr,
    const int* __restrict__ rowp, const int* __restrict__ csrc, const float* __restrict__ cwt,
    const float* __restrict__ We, const float* __restrict__ att, const float* __restrict__ bias,
    float* __restrict__ out, int N, int mode) {
    const int wid = threadIdx.x >> 6;
    const int lane = threadIdx.x & 63;
    const int n = blockIdx.x * 4 + wid;
    if (n >= N) return;
    const int hc0 = lane, hc1 = lane + 64;
    const float LOG2E = 1.4426950408889634f;
    const float we0 = We[hc0], we1 = We[hc1];
    const float at0 = att[hc0] * LOG2E, at1 = att[hc1] * LOG2E;
    const float xr0 = xr[(size_t)n * 128 + hc0];
    const float xr1 = xr[(size_t)n * 128 + hc1];
    float l0 = 0.f, l1 = 0.f, a0 = 0.f, a1 = 0.f;
    const int e0 = __builtin_amdgcn_readfirstlane(rowp[n]);
    const int e1 = __builtin_amdgcn_readfirstlane(rowp[n + 1]);
    for (int e = e0; e < e1; ++e) {
        const int s = csrc[e];          // wave-uniform -> s_load
        const float w = cwt[e];         // wave-uniform -> s_load
        const float* xp = xl + (size_t)s * 128;
        float x0 = xp[hc0];
        float x1 = xp[hc1];
        float z0 = x0 + fmaf(w, we0, xr0);
        float z1 = x1 + fmaf(w, we1, xr1);
        z0 = fmaxf(z0, 0.f) + 0.2f * fminf(z0, 0.f);   // leaky relu
        z1 = fmaxf(z1, 0.f) + 0.2f * fminf(z1, 0.f);
        float p0 = z0 * at0, p1 = z1 * at1;
#pragma unroll
        for (int off = 1; off < 32; off <<= 1) {       // reduce within head group
            p0 += __shfl_xor(p0, off, 64);
            p1 += __shfl_xor(p1, off, 64);
        }
        float q0 = __builtin_amdgcn_exp2f(p0);
        float q1 = __builtin_amdgcn_exp2f(p1);
        l0 += q0;
        l1 += q1;
        a0 = fmaf(q0, x0, a0);
        a1 = fmaf(q1, x1, a1);
    }
    float r0 = a0 / (l0 + 1e-16f);
    float r1 = a1 / (l1 + 1e-16f);
    if (mode == 0) {
        float v0 = r0 + bias[hc0]; v0 = (v0 > 0.f) ? v0 : (__expf(v0) - 1.f);  // ELU
        float v1 = r1 + bias[hc1]; v1 = (v1 > 0.f) ? v1 : (__expf(v1) - 1.f);
        out[(size_t)n * 128 + hc0] = v0;
        out[(size_t)n * 128 + hc1] = v1;
    } else {
        float t = r0 + r1;                 // heads (g, g+2) at channel c=lane&31
        t += __shfl_xor(t, 32, 64);        // + heads from partner half-wave
        if (lane < 32)
            out[(size_t)n * 32 + lane] = 0.25f * t + bias[lane];
    }
}

extern "C" void kernel_launch(void* const* d_in, const int* in_sizes, int n_in,
                              void* d_out, int out_size, void* d_ws, size_t ws_size,
                              hipStream_t stream) {
    const float* x    = (const float*)d_in[0];
    const int*  eidx  = (const int*)d_in[1];
    const float* ew   = (const float*)d_in[2];
    const float* Wl1  = (const float*)d_in[3];
    const float* Wr1  = (const float*)d_in[4];
    const float* We1  = (const float*)d_in[5];
    const float* att1 = (const float*)d_in[6];
    const float* b1   = (const float*)d_in[7];
    const float* Wl2  = (const float*)d_in[8];
    const float* Wr2  = (const float*)d_in[9];
    const float* We2  = (const float*)d_in[10];
    const float* att2 = (const float*)d_in[11];
    const float* b2   = (const float*)d_in[12];

    const int N = in_sizes[0] / 128;
    const int E = in_sizes[1] / 2;
    const int* src = eidx;
    const int* dst = eidx + E;

    char* p = (char*)d_ws;
    auto alloc = [&](size_t bytes) -> void* {
        void* r = (void*)p;
        p += (bytes + 255) & ~(size_t)255;
        return r;
    };
    float* xl     = (float*)alloc((size_t)N * 128 * sizeof(float));
    float* xr     = (float*)alloc((size_t)N * 128 * sizeof(float));
    float* h1     = (float*)alloc((size_t)N * 128 * sizeof(float));
    int*   csrc   = (int*)alloc((size_t)(E + N) * sizeof(int));
    float* cwt    = (float*)alloc((size_t)(E + N) * sizeof(float));
    int*   rowp   = (int*)alloc((size_t)(N + 1) * sizeof(int));
    int*   cursor = (int*)alloc((size_t)N * sizeof(int));
    int*   cnt    = (int*)alloc((size_t)(N + 8) * sizeof(int));
    float* sumbuf = (float*)(cnt + N);
    int*   bsum   = (int*)alloc(256 * sizeof(int));

    hipMemsetAsync(cnt, 0, (size_t)(N + 8) * sizeof(int), stream);

    sum_ew_kernel<<<512, 256, 0, stream>>>(ew, sumbuf, E);
    hist_kernel<<<(E + 255) / 256, 256, 0, stream>>>(dst, cnt, E);

    int nb = (N + 255) / 256;
    scan1_kernel<<<nb, 256, 0, stream>>>(cnt, rowp, bsum, N);
    scan2_kernel<<<1, 256, 0, stream>>>(bsum, nb);
    scan3_kernel<<<nb, 256, 0, stream>>>(rowp, bsum, cursor, N, E);

    scatter_kernel<<<(E + N + 255) / 256, 256, 0, stream>>>(src, dst, ew, sumbuf,
                                                            cursor, csrc, cwt, E, N);

    // Layer 1
    gemm_dual2_kernel<<<(N + 63) / 64, 256, 0, stream>>>(x, Wl1, Wr1, xl, xr, N);
    agg_kernel<<<(N + 3) / 4, 256, 0, stream>>>(xl, xr, rowp, csrc, cwt,
                                                We1, att1, b1, h1, N, 0);
    // Layer 2
    gemm_dual2_kernel<<<(N + 63) / 64, 256, 0, stream>>>(h1, Wl2, Wr2, xl, xr, N);
    agg_kernel<<<(N + 3) / 4, 256, 0, stream>>>(xl, xr, rowp, csrc, cwt,
                                                We2, att2, b2, (float*)d_out, N, 1);
}

// Round 3
// 796.227 us; speedup vs baseline: 1.2522x; 1.1045x over previous
//
#include <hip/hip_runtime.h>
#include <math.h>

// ---------------------------------------------------------------------------
// GATv2 x2 layers.
//   - CSR-by-dst built once (hist+sum -> scan -> atomic scatter), shared by
//     both layers.  Self loops appended with mean(edge_weight).
//   - 2 dual fp32 GEMMs, 8x8 register tiling, A transposed in LDS.
//   - Aggregation: one wave per node; lane l owns head h=l>>4, channels
//     j0=32h+(l&15), j1=j0+16 -> single 4-stage butterfly (xor 1,2,4,8) per
//     edge, one exp, one denominator.  Depth-2 software pipeline on gathers.
// ---------------------------------------------------------------------------

__global__ void hist_sum_kernel(const int* __restrict__ dst, const float* __restrict__ ew,
                                int* __restrict__ cnt, float* __restrict__ sumbuf, int E) {
    float s = 0.f;
    for (int i = blockIdx.x * blockDim.x + threadIdx.x; i < E; i += gridDim.x * blockDim.x) {
        atomicAdd(&cnt[dst[i]], 1);
        s += ew[i];
    }
#pragma unroll
    for (int off = 1; off <= 32; off <<= 1)
        s += __shfl_xor(s, off, 64);
    if ((threadIdx.x & 63) == 0)
        atomicAdd(sumbuf, s);
}

__global__ void scan1_kernel(const int* __restrict__ cnt, int* __restrict__ rowp,
                             int* __restrict__ bsum, int N) {
    __shared__ int sh[256];
    int i = blockIdx.x * 256 + threadIdx.x;
    int v = (i < N) ? (cnt[i] + 1) : 0;
    sh[threadIdx.x] = v;
    __syncthreads();
    for (int off = 1; off < 256; off <<= 1) {
        int y = 0;
        if ((int)threadIdx.x >= off) y = sh[threadIdx.x - off];
        __syncthreads();
        sh[threadIdx.x] += y;
        __syncthreads();
    }
    int incl = sh[threadIdx.x];
    if (i < N) rowp[i] = incl - v;
    if (threadIdx.x == 255) bsum[blockIdx.x] = incl;
}

__global__ void scan2_kernel(int* __restrict__ bsum, int nb) {
    __shared__ int sh[256];
    int v = ((int)threadIdx.x < nb) ? bsum[threadIdx.x] : 0;
    sh[threadIdx.x] = v;
    __syncthreads();
    for (int off = 1; off < 256; off <<= 1) {
        int y = 0;
        if ((int)threadIdx.x >= off) y = sh[threadIdx.x - off];
        __syncthreads();
        sh[threadIdx.x] += y;
        __syncthreads();
    }
    int incl = sh[threadIdx.x];
    if ((int)threadIdx.x < nb) bsum[threadIdx.x] = incl - v;
}

__global__ void scan3_kernel(int* __restrict__ rowp, const int* __restrict__ bsum,
                             int* __restrict__ cursor, int N, int E) {
    int i = blockIdx.x * 256 + threadIdx.x;
    if (i < N) {
        int rp = rowp[i] + bsum[blockIdx.x];
        rowp[i] = rp;
        cursor[i] = rp;
    }
    if (i == 0) rowp[N] = E + N;
}

__global__ void scatter_kernel(const int* __restrict__ src, const int* __restrict__ dst,
                               const float* __restrict__ ew, const float* __restrict__ sumbuf,
                               int* __restrict__ cursor, int* __restrict__ csrc,
                               float* __restrict__ cwt, int E, int N) {
    int i = blockIdx.x * blockDim.x + threadIdx.x;
    if (i < E) {
        int d = dst[i];
        int pos = atomicAdd(&cursor[d], 1);
        csrc[pos] = src[i];
        cwt[pos] = ew[i];
    } else if (i < E + N) {
        int n = i - E;
        int pos = atomicAdd(&cursor[n], 1);
        csrc[pos] = n;
        cwt[pos] = sumbuf[0] * (1.0f / (float)E);
    }
}

// Ya = X @ Wa, Yb = X @ Wb  (X: N x 128, W: 128 x 128 fp32).
__global__ __launch_bounds__(256) void gemm_dual2_kernel(
    const float* __restrict__ X, const float* __restrict__ Wa, const float* __restrict__ Wb,
    float* __restrict__ Ya, float* __restrict__ Yb, int N) {
    __shared__ float At[32][68];   // [k][row]
    const int tid = threadIdx.x;
    const int rb = blockIdx.x * 64;
    const int tx = tid & 31;
    const int ty = tid >> 5;

    float acc[8][8];
#pragma unroll
    for (int r = 0; r < 8; r++)
#pragma unroll
        for (int c = 0; c < 8; c++) acc[r][c] = 0.f;

    for (int k0 = 0; k0 < 128; k0 += 32) {
        __syncthreads();
        for (int i = tid; i < 512; i += 256) {
            int row = i >> 3;
            int kq = i & 7;
            float4 v = make_float4(0.f, 0.f, 0.f, 0.f);
            if (rb + row < N)
                v = ((const float4*)X)[(size_t)(rb + row) * 32 + (k0 >> 2) + kq];
            At[kq * 4 + 0][row] = v.x;
            At[kq * 4 + 1][row] = v.y;
            At[kq * 4 + 2][row] = v.z;
            At[kq * 4 + 3][row] = v.w;
        }
        __syncthreads();
#pragma unroll
        for (int k = 0; k < 32; k++) {
            float4 a0 = *(const float4*)&At[k][ty * 8];
            float4 a1 = *(const float4*)&At[k][ty * 8 + 4];
            float4 b0 = ((const float4*)(Wa + (size_t)(k0 + k) * 128))[tx];
            float4 b1 = ((const float4*)(Wb + (size_t)(k0 + k) * 128))[tx];
            float ar[8] = {a0.x, a0.y, a0.z, a0.w, a1.x, a1.y, a1.z, a1.w};
            float bc[8] = {b0.x, b0.y, b0.z, b0.w, b1.x, b1.y, b1.z, b1.w};
#pragma unroll
            for (int r = 0; r < 8; r++)
#pragma unroll
                for (int c = 0; c < 8; c++)
                    acc[r][c] = fmaf(ar[r], bc[c], acc[r][c]);
        }
    }

#pragma unroll
    for (int r = 0; r < 8; r++) {
        int row = rb + ty * 8 + r;
        if (row < N) {
            ((float4*)Ya)[(size_t)row * 32 + tx] =
                make_float4(acc[r][0], acc[r][1], acc[r][2], acc[r][3]);
            ((float4*)Yb)[(size_t)row * 32 + tx] =
                make_float4(acc[r][4], acc[r][5], acc[r][6], acc[r][7]);
        }
    }
}

// One wave per node. lane l: head h=l>>4, channels j0=32h+(l&15), j1=j0+16.
// Single 4-stage butterfly over 16-lane group; fixed-max softmax (exp(p)).
// mode 0: out[n,128] = elu(res + b)    mode 1: out[n,32] = mean_h(res) + b
__global__ __launch_bounds__(256) void agg_kernel(
    const float* __restrict__ xl, const float* __restrict__ xr,
    const int* __restrict__ rowp, const int* __restrict__ csrc, const float* __restrict__ cwt,
    const float* __restrict__ We, const float* __restrict__ att, const float* __restrict__ bias,
    float* __restrict__ out, int N, int mode) {
    const int wid = threadIdx.x >> 6;
    const int lane = threadIdx.x & 63;
    const int n = blockIdx.x * 4 + wid;
    if (n >= N) return;
    const int j0 = ((lane >> 4) << 5) + (lane & 15);   // 32*h + c
    const int j1 = j0 + 16;
    const float LOG2E = 1.4426950408889634f;
    const float we0 = We[j0], we1 = We[j1];
    const float at0 = att[j0] * LOG2E, at1 = att[j1] * LOG2E;
    const float xr0 = xr[(size_t)n * 128 + j0];
    const float xr1 = xr[(size_t)n * 128 + j1];
    float l0 = 0.f, a0 = 0.f, a1 = 0.f;
    const int e0 = __builtin_amdgcn_readfirstlane(rowp[n]);
    const int e1 = __builtin_amdgcn_readfirstlane(rowp[n + 1]);

    auto process = [&](float x0, float x1, float w) {
        float z0 = x0 + fmaf(w, we0, xr0);
        float z1 = x1 + fmaf(w, we1, xr1);
        z0 = fmaxf(z0, 0.f) + 0.2f * fminf(z0, 0.f);   // leaky relu
        z1 = fmaxf(z1, 0.f) + 0.2f * fminf(z1, 0.f);
        float p = fmaf(z1, at1, z0 * at0);
        p += __shfl_xor(p, 1, 64);
        p += __shfl_xor(p, 2, 64);
        p += __shfl_xor(p, 4, 64);
        p += __shfl_xor(p, 8, 64);
        float q = __builtin_amdgcn_exp2f(p);
        l0 += q;
        a0 = fmaf(q, x0, a0);
        a1 = fmaf(q, x1, a1);
    };

    // depth-2 software pipeline
    int s = csrc[e0];
    float w = cwt[e0];
    const float* xp = xl + (size_t)s * 128;
    float x0 = xp[j0], x1 = xp[j1];
    for (int e = e0 + 1; e < e1; ++e) {
        int s2 = csrc[e];
        float w2 = cwt[e];
        const float* xp2 = xl + (size_t)s2 * 128;
        float y0 = xp2[j0], y1 = xp2[j1];
        process(x0, x1, w);
        x0 = y0; x1 = y1; w = w2;
    }
    process(x0, x1, w);

    float rdenom = 1.0f / (l0 + 1e-16f);
    float r0 = a0 * rdenom;
    float r1 = a1 * rdenom;
    if (mode == 0) {
        float v0 = r0 + bias[j0]; v0 = (v0 > 0.f) ? v0 : (__expf(v0) - 1.f);  // ELU
        float v1 = r1 + bias[j1]; v1 = (v1 > 0.f) ? v1 : (__expf(v1) - 1.f);
        out[(size_t)n * 128 + j0] = v0;
        out[(size_t)n * 128 + j1] = v1;
    } else {
        float t0 = r0, t1 = r1;            // mean over 4 heads: sum across groups
        t0 += __shfl_xor(t0, 16, 64);
        t0 += __shfl_xor(t0, 32, 64);
        t1 += __shfl_xor(t1, 16, 64);
        t1 += __shfl_xor(t1, 32, 64);
        if (lane < 16) {
            out[(size_t)n * 32 + lane]      = 0.25f * t0 + bias[lane];
            out[(size_t)n * 32 + lane + 16] = 0.25f * t1 + bias[lane + 16];
        }
    }
}

extern "C" void kernel_launch(void* const* d_in, const int* in_sizes, int n_in,
                              void* d_out, int out_size, void* d_ws, size_t ws_size,
                              hipStream_t stream) {
    const float* x    = (const float*)d_in[0];
    const int*  eidx  = (const int*)d_in[1];
    const float* ew   = (const float*)d_in[2];
    const float* Wl1  = (const float*)d_in[3];
    const float* Wr1  = (const float*)d_in[4];
    const float* We1  = (const float*)d_in[5];
    const float* att1 = (const float*)d_in[6];
    const float* b1   = (const float*)d_in[7];
    const float* Wl2  = (const float*)d_in[8];
    const float* Wr2  = (const float*)d_in[9];
    const float* We2  = (const float*)d_in[10];
    const float* att2 = (const float*)d_in[11];
    const float* b2   = (const float*)d_in[12];

    const int N = in_sizes[0] / 128;
    const int E = in_sizes[1] / 2;
    const int* src = eidx;
    const int* dst = eidx + E;

    char* p = (char*)d_ws;
    auto alloc = [&](size_t bytes) -> void* {
        void* r = (void*)p;
        p += (bytes + 255) & ~(size_t)255;
        return r;
    };
    float* xl     = (float*)alloc((size_t)N * 128 * sizeof(float));
    float* xr     = (float*)alloc((size_t)N * 128 * sizeof(float));
    float* h1     = (float*)alloc((size_t)N * 128 * sizeof(float));
    int*   csrc   = (int*)alloc((size_t)(E + N) * sizeof(int));
    float* cwt    = (float*)alloc((size_t)(E + N) * sizeof(float));
    int*   rowp   = (int*)alloc((size_t)(N + 1) * sizeof(int));
    int*   cursor = (int*)alloc((size_t)N * sizeof(int));
    int*   cnt    = (int*)alloc((size_t)(N + 8) * sizeof(int));
    float* sumbuf = (float*)(cnt + N);
    int*   bsum   = (int*)alloc(256 * sizeof(int));

    hipMemsetAsync(cnt, 0, (size_t)(N + 8) * sizeof(int), stream);

    hist_sum_kernel<<<1024, 256, 0, stream>>>(dst, ew, cnt, sumbuf, E);

    int nb = (N + 255) / 256;
    scan1_kernel<<<nb, 256, 0, stream>>>(cnt, rowp, bsum, N);
    scan2_kernel<<<1, 256, 0, stream>>>(bsum, nb);
    scan3_kernel<<<nb, 256, 0, stream>>>(rowp, bsum, cursor, N, E);

    scatter_kernel<<<(E + N + 255) / 256, 256, 0, stream>>>(src, dst, ew, sumbuf,
                                                            cursor, csrc, cwt, E, N);

    // Layer 1
    gemm_dual2_kernel<<<(N + 63) / 64, 256, 0, stream>>>(x, Wl1, Wr1, xl, xr, N);
    agg_kernel<<<(N + 3) / 4, 256, 0, stream>>>(xl, xr, rowp, csrc, cwt,
                                                We1, att1, b1, h1, N, 0);
    // Layer 2
    gemm_dual2_kernel<<<(N + 63) / 64, 256, 0, stream>>>(h1, Wl2, Wr2, xl, xr, N);
    agg_kernel<<<(N + 3) / 4, 256, 0, stream>>>(xl, xr, rowp, csrc, cwt,
                                                We2, att2, b2, (float*)d_out, N, 1);
}

// Round 4
// 722.038 us; speedup vs baseline: 1.3809x; 1.1027x over previous
//
#include <hip/hip_runtime.h>
#include <math.h>

// ---------------------------------------------------------------------------
// GATv2 x2 layers.
//   - CSR-by-dst built once (hist+sum -> scan -> atomic scatter), shared by
//     both layers.  Self loops appended with mean(edge_weight).  Edge record
//     packed (src,int-cast weight) as int2 -> one 8B store / 8B load.
//   - 2 dual fp32 GEMMs, 8x8 register tiling, A transposed in LDS.
//   - Aggregation: one wave per node; lane l owns head h=l>>4, channels
//     j0=32h+2c, j0+1 (c=l&15) -> one dwordx2 gather per edge; 16-lane logit
//     reduction via DPP adds (quad_perm xor1/xor2, row_ror:4/:8) on the VALU
//     pipe -- no LDS-pipe swizzles in the hot loop.  Depth-2 load pipeline.
// ---------------------------------------------------------------------------

__global__ void hist_sum_kernel(const int* __restrict__ dst, const float* __restrict__ ew,
                                int* __restrict__ cnt, float* __restrict__ sumbuf, int E) {
    float s = 0.f;
    for (int i = blockIdx.x * blockDim.x + threadIdx.x; i < E; i += gridDim.x * blockDim.x) {
        atomicAdd(&cnt[dst[i]], 1);
        s += ew[i];
    }
#pragma unroll
    for (int off = 1; off <= 32; off <<= 1)
        s += __shfl_xor(s, off, 64);
    if ((threadIdx.x & 63) == 0)
        atomicAdd(sumbuf, s);
}

__global__ void scan1_kernel(const int* __restrict__ cnt, int* __restrict__ rowp,
                             int* __restrict__ bsum, int N) {
    __shared__ int sh[256];
    int i = blockIdx.x * 256 + threadIdx.x;
    int v = (i < N) ? (cnt[i] + 1) : 0;
    sh[threadIdx.x] = v;
    __syncthreads();
    for (int off = 1; off < 256; off <<= 1) {
        int y = 0;
        if ((int)threadIdx.x >= off) y = sh[threadIdx.x - off];
        __syncthreads();
        sh[threadIdx.x] += y;
        __syncthreads();
    }
    int incl = sh[threadIdx.x];
    if (i < N) rowp[i] = incl - v;
    if (threadIdx.x == 255) bsum[blockIdx.x] = incl;
}

__global__ void scan2_kernel(int* __restrict__ bsum, int nb) {
    __shared__ int sh[256];
    int v = ((int)threadIdx.x < nb) ? bsum[threadIdx.x] : 0;
    sh[threadIdx.x] = v;
    __syncthreads();
    for (int off = 1; off < 256; off <<= 1) {
        int y = 0;
        if ((int)threadIdx.x >= off) y = sh[threadIdx.x - off];
        __syncthreads();
        sh[threadIdx.x] += y;
        __syncthreads();
    }
    int incl = sh[threadIdx.x];
    if ((int)threadIdx.x < nb) bsum[threadIdx.x] = incl - v;
}

__global__ void scan3_kernel(int* __restrict__ rowp, const int* __restrict__ bsum,
                             int* __restrict__ cursor, int N, int E) {
    int i = blockIdx.x * 256 + threadIdx.x;
    if (i < N) {
        int rp = rowp[i] + bsum[blockIdx.x];
        rowp[i] = rp;
        cursor[i] = rp;
    }
    if (i == 0) rowp[N] = E + N;
}

__global__ void scatter_kernel(const int* __restrict__ src, const int* __restrict__ dst,
                               const float* __restrict__ ew, const float* __restrict__ sumbuf,
                               int* __restrict__ cursor, int2* __restrict__ crec,
                               int E, int N) {
    int i = blockIdx.x * blockDim.x + threadIdx.x;
    if (i < E) {
        int d = dst[i];
        int pos = atomicAdd(&cursor[d], 1);
        crec[pos] = make_int2(src[i], __float_as_int(ew[i]));
    } else if (i < E + N) {
        int n = i - E;
        int pos = atomicAdd(&cursor[n], 1);
        crec[pos] = make_int2(n, __float_as_int(sumbuf[0] * (1.0f / (float)E)));
    }
}

// Ya = X @ Wa, Yb = X @ Wb  (X: N x 128, W: 128 x 128 fp32).
__global__ __launch_bounds__(256) void gemm_dual2_kernel(
    const float* __restrict__ X, const float* __restrict__ Wa, const float* __restrict__ Wb,
    float* __restrict__ Ya, float* __restrict__ Yb, int N) {
    __shared__ float At[32][68];   // [k][row]
    const int tid = threadIdx.x;
    const int rb = blockIdx.x * 64;
    const int tx = tid & 31;
    const int ty = tid >> 5;

    float acc[8][8];
#pragma unroll
    for (int r = 0; r < 8; r++)
#pragma unroll
        for (int c = 0; c < 8; c++) acc[r][c] = 0.f;

    for (int k0 = 0; k0 < 128; k0 += 32) {
        __syncthreads();
        for (int i = tid; i < 512; i += 256) {
            int row = i >> 3;
            int kq = i & 7;
            float4 v = make_float4(0.f, 0.f, 0.f, 0.f);
            if (rb + row < N)
                v = ((const float4*)X)[(size_t)(rb + row) * 32 + (k0 >> 2) + kq];
            At[kq * 4 + 0][row] = v.x;
            At[kq * 4 + 1][row] = v.y;
            At[kq * 4 + 2][row] = v.z;
            At[kq * 4 + 3][row] = v.w;
        }
        __syncthreads();
#pragma unroll
        for (int k = 0; k < 32; k++) {
            float4 a0 = *(const float4*)&At[k][ty * 8];
            float4 a1 = *(const float4*)&At[k][ty * 8 + 4];
            float4 b0 = ((const float4*)(Wa + (size_t)(k0 + k) * 128))[tx];
            float4 b1 = ((const float4*)(Wb + (size_t)(k0 + k) * 128))[tx];
            float ar[8] = {a0.x, a0.y, a0.z, a0.w, a1.x, a1.y, a1.z, a1.w};
            float bc[8] = {b0.x, b0.y, b0.z, b0.w, b1.x, b1.y, b1.z, b1.w};
#pragma unroll
            for (int r = 0; r < 8; r++)
#pragma unroll
                for (int c = 0; c < 8; c++)
                    acc[r][c] = fmaf(ar[r], bc[c], acc[r][c]);
        }
    }

#pragma unroll
    for (int r = 0; r < 8; r++) {
        int row = rb + ty * 8 + r;
        if (row < N) {
            ((float4*)Ya)[(size_t)row * 32 + tx] =
                make_float4(acc[r][0], acc[r][1], acc[r][2], acc[r][3]);
            ((float4*)Yb)[(size_t)row * 32 + tx] =
                make_float4(acc[r][4], acc[r][5], acc[r][6], acc[r][7]);
        }
    }
}

// DPP partial-sum step: v += lane-permuted(v) within 16-lane rows. VALU-pipe.
template <int CTRL>
__device__ __forceinline__ float dpp_sum_step(float v) {
    int t = __builtin_amdgcn_update_dpp(0, __float_as_int(v), CTRL, 0xF, 0xF, true);
    return v + __int_as_float(t);
}

// One wave per node. lane l: head h=l>>4, c=l&15, channels j0=32h+2c, j0+1.
// 16-lane logit sum via DPP (quad_perm xor1, xor2, row_ror:4, row_ror:8).
// Fixed-max softmax (exp(p)); logits bounded so no max subtraction needed.
// mode 0: out[n,128] = elu(res + b)    mode 1: out[n,32] = mean_h(res) + b
__global__ __launch_bounds__(256) void agg_kernel(
    const float* __restrict__ xl, const float* __restrict__ xr,
    const int* __restrict__ rowp, const int2* __restrict__ crec,
    const float* __restrict__ We, const float* __restrict__ att, const float* __restrict__ bias,
    float* __restrict__ out, int N, int mode) {
    const int wid = threadIdx.x >> 6;
    const int lane = threadIdx.x & 63;
    const int n = blockIdx.x * 4 + wid;
    if (n >= N) return;
    const int j0 = ((lane >> 4) << 5) + ((lane & 15) << 1);   // 32h + 2c
    const float LOG2E = 1.4426950408889634f;
    const float2 we = *(const float2*)(We + j0);
    float2 at = *(const float2*)(att + j0);
    const float at0 = at.x * LOG2E, at1 = at.y * LOG2E;
    const float2 xrv = *(const float2*)(xr + (size_t)n * 128 + j0);
    float l0 = 0.f, a0 = 0.f, a1 = 0.f;
    const int e0 = __builtin_amdgcn_readfirstlane(rowp[n]);
    const int e1 = __builtin_amdgcn_readfirstlane(rowp[n + 1]);

    auto process = [&](float2 xv, float w) {
        float z0 = xv.x + fmaf(w, we.x, xrv.x);
        float z1 = xv.y + fmaf(w, we.y, xrv.y);
        z0 = fmaxf(z0, 0.f) + 0.2f * fminf(z0, 0.f);   // leaky relu
        z1 = fmaxf(z1, 0.f) + 0.2f * fminf(z1, 0.f);
        float p = fmaf(z1, at1, z0 * at0);
        p = dpp_sum_step<0xB1>(p);    // quad_perm [1,0,3,2]  (xor 1)
        p = dpp_sum_step<0x4E>(p);    // quad_perm [2,3,0,1]  (xor 2)
        p = dpp_sum_step<0x124>(p);   // row_ror:4
        p = dpp_sum_step<0x128>(p);   // row_ror:8
        float q = __builtin_amdgcn_exp2f(p);
        l0 += q;
        a0 = fmaf(q, xv.x, a0);
        a1 = fmaf(q, xv.y, a1);
    };

    // depth-2 software pipeline
    int2 r = crec[e0];
    float2 xv = *(const float2*)(xl + (size_t)r.x * 128 + j0);
    float w = __int_as_float(r.y);
    for (int e = e0 + 1; e < e1; ++e) {
        int2 r2 = crec[e];
        float2 xv2 = *(const float2*)(xl + (size_t)r2.x * 128 + j0);
        float w2 = __int_as_float(r2.y);
        process(xv, w);
        xv = xv2; w = w2;
    }
    process(xv, w);

    float rdenom = 1.0f / (l0 + 1e-16f);
    float r0 = a0 * rdenom;
    float r1 = a1 * rdenom;
    if (mode == 0) {
        float2 bv = *(const float2*)(bias + j0);
        float v0 = r0 + bv.x; v0 = (v0 > 0.f) ? v0 : (__expf(v0) - 1.f);  // ELU
        float v1 = r1 + bv.y; v1 = (v1 > 0.f) ? v1 : (__expf(v1) - 1.f);
        *(float2*)(out + (size_t)n * 128 + j0) = make_float2(v0, v1);
    } else {
        float t0 = r0, t1 = r1;            // mean over 4 heads (lane>>4 groups)
        t0 += __shfl_xor(t0, 16, 64);
        t0 += __shfl_xor(t0, 32, 64);
        t1 += __shfl_xor(t1, 16, 64);
        t1 += __shfl_xor(t1, 32, 64);
        if (lane < 16) {
            int c2 = lane << 1;
            float2 bv = *(const float2*)(bias + c2);
            *(float2*)(out + (size_t)n * 32 + c2) =
                make_float2(0.25f * t0 + bv.x, 0.25f * t1 + bv.y);
        }
    }
}

extern "C" void kernel_launch(void* const* d_in, const int* in_sizes, int n_in,
                              void* d_out, int out_size, void* d_ws, size_t ws_size,
                              hipStream_t stream) {
    const float* x    = (const float*)d_in[0];
    const int*  eidx  = (const int*)d_in[1];
    const float* ew   = (const float*)d_in[2];
    const float* Wl1  = (const float*)d_in[3];
    const float* Wr1  = (const float*)d_in[4];
    const float* We1  = (const float*)d_in[5];
    const float* att1 = (const float*)d_in[6];
    const float* b1   = (const float*)d_in[7];
    const float* Wl2  = (const float*)d_in[8];
    const float* Wr2  = (const float*)d_in[9];
    const float* We2  = (const float*)d_in[10];
    const float* att2 = (const float*)d_in[11];
    const float* b2   = (const float*)d_in[12];

    const int N = in_sizes[0] / 128;
    const int E = in_sizes[1] / 2;
    const int* src = eidx;
    const int* dst = eidx + E;

    char* p = (char*)d_ws;
    auto alloc = [&](size_t bytes) -> void* {
        void* r = (void*)p;
        p += (bytes + 255) & ~(size_t)255;
        return r;
    };
    float* xl     = (float*)alloc((size_t)N * 128 * sizeof(float));
    float* xr     = (float*)alloc((size_t)N * 128 * sizeof(float));
    float* h1     = (float*)alloc((size_t)N * 128 * sizeof(float));
    int2*  crec   = (int2*)alloc((size_t)(E + N) * sizeof(int2));
    int*   rowp   = (int*)alloc((size_t)(N + 1) * sizeof(int));
    int*   cursor = (int*)alloc((size_t)N * sizeof(int));
    int*   cnt    = (int*)alloc((size_t)(N + 8) * sizeof(int));
    float* sumbuf = (float*)(cnt + N);
    int*   bsum   = (int*)alloc(256 * sizeof(int));

    hipMemsetAsync(cnt, 0, (size_t)(N + 8) * sizeof(int), stream);

    hist_sum_kernel<<<1024, 256, 0, stream>>>(dst, ew, cnt, sumbuf, E);

    int nb = (N + 255) / 256;
    scan1_kernel<<<nb, 256, 0, stream>>>(cnt, rowp, bsum, N);
    scan2_kernel<<<1, 256, 0, stream>>>(bsum, nb);
    scan3_kernel<<<nb, 256, 0, stream>>>(rowp, bsum, cursor, N, E);

    scatter_kernel<<<(E + N + 255) / 256, 256, 0, stream>>>(src, dst, ew, sumbuf,
                                                            cursor, crec, E, N);

    // Layer 1
    gemm_dual2_kernel<<<(N + 63) / 64, 256, 0, stream>>>(x, Wl1, Wr1, xl, xr, N);
    agg_kernel<<<(N + 3) / 4, 256, 0, stream>>>(xl, xr, rowp, crec,
                                                We1, att1, b1, h1, N, 0);
    // Layer 2
    gemm_dual2_kernel<<<(N + 63) / 64, 256, 0, stream>>>(h1, Wl2, Wr2, xl, xr, N);
    agg_kernel<<<(N + 3) / 4, 256, 0, stream>>>(xl, xr, rowp, crec,
                                                We2, att2, b2, (float*)d_out, N, 1);
}

// Round 6
// 582.467 us; speedup vs baseline: 1.7118x; 1.2396x over previous
//
#include <hip/hip_runtime.h>
#include <hip/hip_fp16.h>
#include <math.h>

// ---------------------------------------------------------------------------
// GATv2 x2 layers.
//   - CSR-by-dst built once (hist+sum -> scan -> atomic scatter), shared by
//     both layers.  Self loops appended with mean(edge_weight).  Edge record
//     packed (src, weight bits) as int2.
//   - 2 dual fp32 GEMMs, 8x8 register tiling; source-transform output (xl)
//     stored as packed fp16 (halves gather traffic), target-transform (xr)
//     stays fp32.
//   - Aggregation: one wave per node; lane l owns head h=l>>4, channels
//     j0=32h+2c, j0+1 -> one half2 (4B) gather per edge; 16-lane logit sum
//     via DPP adds on the VALU pipe; depth-4 rolling prefetch pipeline.
//   - R6 fix: Yh epilogue row stride is 32 uint2 (128 halves), was 16 (bug).
// ---------------------------------------------------------------------------

__global__ void hist_sum_kernel(const int* __restrict__ dst, const float* __restrict__ ew,
                                int* __restrict__ cnt, float* __restrict__ sumbuf, int E) {
    float s = 0.f;
    for (int i = blockIdx.x * blockDim.x + threadIdx.x; i < E; i += gridDim.x * blockDim.x) {
        atomicAdd(&cnt[dst[i]], 1);
        s += ew[i];
    }
#pragma unroll
    for (int off = 1; off <= 32; off <<= 1)
        s += __shfl_xor(s, off, 64);
    if ((threadIdx.x & 63) == 0)
        atomicAdd(sumbuf, s);
}

__global__ void scan1_kernel(const int* __restrict__ cnt, int* __restrict__ rowp,
                             int* __restrict__ bsum, int N) {
    __shared__ int sh[256];
    int i = blockIdx.x * 256 + threadIdx.x;
    int v = (i < N) ? (cnt[i] + 1) : 0;
    sh[threadIdx.x] = v;
    __syncthreads();
    for (int off = 1; off < 256; off <<= 1) {
        int y = 0;
        if ((int)threadIdx.x >= off) y = sh[threadIdx.x - off];
        __syncthreads();
        sh[threadIdx.x] += y;
        __syncthreads();
    }
    int incl = sh[threadIdx.x];
    if (i < N) rowp[i] = incl - v;
    if (threadIdx.x == 255) bsum[blockIdx.x] = incl;
}

__global__ void scan2_kernel(int* __restrict__ bsum, int nb) {
    __shared__ int sh[256];
    int v = ((int)threadIdx.x < nb) ? bsum[threadIdx.x] : 0;
    sh[threadIdx.x] = v;
    __syncthreads();
    for (int off = 1; off < 256; off <<= 1) {
        int y = 0;
        if ((int)threadIdx.x >= off) y = sh[threadIdx.x - off];
        __syncthreads();
        sh[threadIdx.x] += y;
        __syncthreads();
    }
    int incl = sh[threadIdx.x];
    if ((int)threadIdx.x < nb) bsum[threadIdx.x] = incl - v;
}

__global__ void scan3_kernel(int* __restrict__ rowp, const int* __restrict__ bsum,
                             int* __restrict__ cursor, int N, int E) {
    int i = blockIdx.x * 256 + threadIdx.x;
    if (i < N) {
        int rp = rowp[i] + bsum[blockIdx.x];
        rowp[i] = rp;
        cursor[i] = rp;
    }
    if (i == 0) rowp[N] = E + N;
}

__global__ void scatter_kernel(const int* __restrict__ src, const int* __restrict__ dst,
                               const float* __restrict__ ew, const float* __restrict__ sumbuf,
                               int* __restrict__ cursor, int2* __restrict__ crec,
                               int E, int N) {
    int i = blockIdx.x * blockDim.x + threadIdx.x;
    if (i < E) {
        int d = dst[i];
        int pos = atomicAdd(&cursor[d], 1);
        crec[pos] = make_int2(src[i], __float_as_int(ew[i]));
    } else if (i < E + N) {
        int n = i - E;
        int pos = atomicAdd(&cursor[n], 1);
        crec[pos] = make_int2(n, __float_as_int(sumbuf[0] * (1.0f / (float)E)));
    }
}

// Yh = half(X @ Wa)  [N x 128 fp16], Yb = X @ Wb  [N x 128 fp32].
__global__ __launch_bounds__(256) void gemm_dual2_kernel(
    const float* __restrict__ X, const float* __restrict__ Wa, const float* __restrict__ Wb,
    __half* __restrict__ Yh, float* __restrict__ Yb, int N) {
    __shared__ float At[32][68];   // [k][row]
    const int tid = threadIdx.x;
    const int rb = blockIdx.x * 64;
    const int tx = tid & 31;
    const int ty = tid >> 5;

    float acc[8][8];
#pragma unroll
    for (int r = 0; r < 8; r++)
#pragma unroll
        for (int c = 0; c < 8; c++) acc[r][c] = 0.f;

    for (int k0 = 0; k0 < 128; k0 += 32) {
        __syncthreads();
        for (int i = tid; i < 512; i += 256) {
            int row = i >> 3;
            int kq = i & 7;
            float4 v = make_float4(0.f, 0.f, 0.f, 0.f);
            if (rb + row < N)
                v = ((const float4*)X)[(size_t)(rb + row) * 32 + (k0 >> 2) + kq];
            At[kq * 4 + 0][row] = v.x;
            At[kq * 4 + 1][row] = v.y;
            At[kq * 4 + 2][row] = v.z;
            At[kq * 4 + 3][row] = v.w;
        }
        __syncthreads();
#pragma unroll
        for (int k = 0; k < 32; k++) {
            float4 a0 = *(const float4*)&At[k][ty * 8];
            float4 a1 = *(const float4*)&At[k][ty * 8 + 4];
            float4 b0 = ((const float4*)(Wa + (size_t)(k0 + k) * 128))[tx];
            float4 b1 = ((const float4*)(Wb + (size_t)(k0 + k) * 128))[tx];
            float ar[8] = {a0.x, a0.y, a0.z, a0.w, a1.x, a1.y, a1.z, a1.w};
            float bc[8] = {b0.x, b0.y, b0.z, b0.w, b1.x, b1.y, b1.z, b1.w};
#pragma unroll
            for (int r = 0; r < 8; r++)
#pragma unroll
                for (int c = 0; c < 8; c++)
                    acc[r][c] = fmaf(ar[r], bc[c], acc[r][c]);
        }
    }

#pragma unroll
    for (int r = 0; r < 8; r++) {
        int row = rb + ty * 8 + r;
        if (row < N) {
            __half2 h01, h23;
            h01.x = __float2half_rn(acc[r][0]); h01.y = __float2half_rn(acc[r][1]);
            h23.x = __float2half_rn(acc[r][2]); h23.y = __float2half_rn(acc[r][3]);
            __half2 hp[2] = {h01, h23};
            ((uint2*)Yh)[(size_t)row * 32 + tx] = *(uint2*)hp;   // 32 uint2/row (128 halves)
            ((float4*)Yb)[(size_t)row * 32 + tx] =
                make_float4(acc[r][4], acc[r][5], acc[r][6], acc[r][7]);
        }
    }
}

// DPP partial-sum step: v += lane-permuted(v) within 16-lane rows. VALU-pipe.
template <int CTRL>
__device__ __forceinline__ float dpp_sum_step(float v) {
    int t = __builtin_amdgcn_update_dpp(0, __float_as_int(v), CTRL, 0xF, 0xF, true);
    return v + __int_as_float(t);
}

// One wave per node. lane l: head h=l>>4, c=l&15, channels j0=32h+2c, j0+1.
// fp16 xl gather (half2 / 4B per lane); DPP 16-lane logit sum; depth-4
// rolling prefetch pipeline over the CSR edge list.
// mode 0: out[n,128] = elu(res + b)    mode 1: out[n,32] = mean_h(res) + b
__global__ __launch_bounds__(256) void agg_kernel(
    const __half* __restrict__ xlh, const float* __restrict__ xr,
    const int* __restrict__ rowp, const int2* __restrict__ crec,
    const float* __restrict__ We, const float* __restrict__ att, const float* __restrict__ bias,
    float* __restrict__ out, int N, int mode) {
    const int wid = threadIdx.x >> 6;
    const int lane = threadIdx.x & 63;
    const int n = blockIdx.x * 4 + wid;
    if (n >= N) return;
    const int j0 = ((lane >> 4) << 5) + ((lane & 15) << 1);   // 32h + 2c
    const float LOG2E = 1.4426950408889634f;
    const float2 we = *(const float2*)(We + j0);
    float2 at = *(const float2*)(att + j0);
    const float at0 = at.x * LOG2E, at1 = at.y * LOG2E;
    const float2 xrv = *(const float2*)(xr + (size_t)n * 128 + j0);
    float l0 = 0.f, a0 = 0.f, a1 = 0.f;
    const int e0 = __builtin_amdgcn_readfirstlane(rowp[n]);
    const int e1 = __builtin_amdgcn_readfirstlane(rowp[n + 1]);
    const int cnt = e1 - e0;

    auto gather = [&](int s) -> unsigned {
        return *(const unsigned*)(xlh + (size_t)s * 128 + j0);   // half2
    };
    auto process = [&](unsigned xb, float w) {
        float2 xv = __half22float2(*(__half2*)&xb);
        float z0 = xv.x + fmaf(w, we.x, xrv.x);
        float z1 = xv.y + fmaf(w, we.y, xrv.y);
        z0 = fmaxf(z0, 0.f) + 0.2f * fminf(z0, 0.f);   // leaky relu
        z1 = fmaxf(z1, 0.f) + 0.2f * fminf(z1, 0.f);
        float p = fmaf(z1, at1, z0 * at0);
        p = dpp_sum_step<0xB1>(p);    // quad_perm [1,0,3,2]  (xor 1)
        p = dpp_sum_step<0x4E>(p);    // quad_perm [2,3,0,1]  (xor 2)
        p = dpp_sum_step<0x124>(p);   // row_ror:4
        p = dpp_sum_step<0x128>(p);   // row_ror:8
        float q = __builtin_amdgcn_exp2f(p);
        l0 += q;
        a0 = fmaf(q, xv.x, a0);
        a1 = fmaf(q, xv.y, a1);
    };

    if (cnt >= 4) {
        int e = e0;
        int2 r0 = crec[e], r1 = crec[e + 1], r2 = crec[e + 2], r3 = crec[e + 3];
        unsigned b0 = gather(r0.x), b1 = gather(r1.x), b2 = gather(r2.x), b3 = gather(r3.x);
        float w0 = __int_as_float(r0.y), w1 = __int_as_float(r1.y);
        float w2 = __int_as_float(r2.y), w3 = __int_as_float(r3.y);
        e += 4;
        int done = 0;
        while (cnt - done >= 8) {
            int2 s0 = crec[e], s1 = crec[e + 1], s2 = crec[e + 2], s3 = crec[e + 3];
            unsigned n0 = gather(s0.x), n1 = gather(s1.x), n2 = gather(s2.x), n3 = gather(s3.x);
            process(b0, w0); process(b1, w1); process(b2, w2); process(b3, w3);
            b0 = n0; w0 = __int_as_float(s0.y);
            b1 = n1; w1 = __int_as_float(s1.y);
            b2 = n2; w2 = __int_as_float(s2.y);
            b3 = n3; w3 = __int_as_float(s3.y);
            e += 4; done += 4;
        }
        int extra = cnt - done - 4;   // 0..3 unfetched
        unsigned n0 = 0, n1 = 0, n2 = 0;
        float v0 = 0.f, v1 = 0.f, v2 = 0.f;
        if (extra > 0) { int2 r = crec[e];     n0 = gather(r.x); v0 = __int_as_float(r.y); }
        if (extra > 1) { int2 r = crec[e + 1]; n1 = gather(r.x); v1 = __int_as_float(r.y); }
        if (extra > 2) { int2 r = crec[e + 2]; n2 = gather(r.x); v2 = __int_as_float(r.y); }
        process(b0, w0); process(b1, w1); process(b2, w2); process(b3, w3);
        if (extra > 0) process(n0, v0);
        if (extra > 1) process(n1, v1);
        if (extra > 2) process(n2, v2);
    } else {
        for (int e = e0; e < e1; ++e) {
            int2 r = crec[e];
            process(gather(r.x), __int_as_float(r.y));
        }
    }

    float rdenom = 1.0f / (l0 + 1e-16f);
    float r0 = a0 * rdenom;
    float r1 = a1 * rdenom;
    if (mode == 0) {
        float2 bv = *(const float2*)(bias + j0);
        float v0 = r0 + bv.x; v0 = (v0 > 0.f) ? v0 : (__expf(v0) - 1.f);  // ELU
        float v1 = r1 + bv.y; v1 = (v1 > 0.f) ? v1 : (__expf(v1) - 1.f);
        *(float2*)(out + (size_t)n * 128 + j0) = make_float2(v0, v1);
    } else {
        float t0 = r0, t1 = r1;            // mean over 4 heads (lane>>4 groups)
        t0 += __shfl_xor(t0, 16, 64);
        t0 += __shfl_xor(t0, 32, 64);
        t1 += __shfl_xor(t1, 16, 64);
        t1 += __shfl_xor(t1, 32, 64);
        if (lane < 16) {
            int c2 = lane << 1;
            float2 bv = *(const float2*)(bias + c2);
            *(float2*)(out + (size_t)n * 32 + c2) =
                make_float2(0.25f * t0 + bv.x, 0.25f * t1 + bv.y);
        }
    }
}

extern "C" void kernel_launch(void* const* d_in, const int* in_sizes, int n_in,
                              void* d_out, int out_size, void* d_ws, size_t ws_size,
                              hipStream_t stream) {
    const float* x    = (const float*)d_in[0];
    const int*  eidx  = (const int*)d_in[1];
    const float* ew   = (const float*)d_in[2];
    const float* Wl1  = (const float*)d_in[3];
    const float* Wr1  = (const float*)d_in[4];
    const float* We1  = (const float*)d_in[5];
    const float* att1 = (const float*)d_in[6];
    const float* b1   = (const float*)d_in[7];
    const float* Wl2  = (const float*)d_in[8];
    const float* Wr2  = (const float*)d_in[9];
    const float* We2  = (const float*)d_in[10];
    const float* att2 = (const float*)d_in[11];
    const float* b2   = (const float*)d_in[12];

    const int N = in_sizes[0] / 128;
    const int E = in_sizes[1] / 2;
    const int* src = eidx;
    const int* dst = eidx + E;

    char* p = (char*)d_ws;
    auto alloc = [&](size_t bytes) -> void* {
        void* r = (void*)p;
        p += (bytes + 255) & ~(size_t)255;
        return r;
    };
    __half* xlh   = (__half*)alloc((size_t)N * 128 * sizeof(__half));
    float* xr     = (float*)alloc((size_t)N * 128 * sizeof(float));
    float* h1     = (float*)alloc((size_t)N * 128 * sizeof(float));
    int2*  crec   = (int2*)alloc((size_t)(E + N) * sizeof(int2));
    int*   rowp   = (int*)alloc((size_t)(N + 1) * sizeof(int));
    int*   cursor = (int*)alloc((size_t)N * sizeof(int));
    int*   cnt    = (int*)alloc((size_t)(N + 8) * sizeof(int));
    float* sumbuf = (float*)(cnt + N);
    int*   bsum   = (int*)alloc(256 * sizeof(int));

    hipMemsetAsync(cnt, 0, (size_t)(N + 8) * sizeof(int), stream);

    hist_sum_kernel<<<1024, 256, 0, stream>>>(dst, ew, cnt, sumbuf, E);

    int nb = (N + 255) / 256;
    scan1_kernel<<<nb, 256, 0, stream>>>(cnt, rowp, bsum, N);
    scan2_kernel<<<1, 256, 0, stream>>>(bsum, nb);
    scan3_kernel<<<nb, 256, 0, stream>>>(rowp, bsum, cursor, N, E);

    scatter_kernel<<<(E + N + 255) / 256, 256, 0, stream>>>(src, dst, ew, sumbuf,
                                                            cursor, crec, E, N);

    // Layer 1
    gemm_dual2_kernel<<<(N + 63) / 64, 256, 0, stream>>>(x, Wl1, Wr1, xlh, xr, N);
    agg_kernel<<<(N + 3) / 4, 256, 0, stream>>>(xlh, xr, rowp, crec,
                                                We1, att1, b1, h1, N, 0);
    // Layer 2
    gemm_dual2_kernel<<<(N + 63) / 64, 256, 0, stream>>>(h1, Wl2, Wr2, xlh, xr, N);
    agg_kernel<<<(N + 3) / 4, 256, 0, stream>>>(xlh, xr, rowp, crec,
                                                We2, att2, b2, (float*)d_out, N, 1);
}

// Round 7
// 474.389 us; speedup vs baseline: 2.1018x; 1.2278x over previous
//
#include <hip/hip_runtime.h>
#include <hip/hip_fp16.h>
#include <math.h>

// ---------------------------------------------------------------------------
// GATv2 x2 layers.
//   - CSR-by-dst via two-level counting sort (NO random global atomics):
//       bucket_hist (LDS 256-way, dst>>8) -> bucket_scan -> partition (LDS
//       hist + 1 global atomic per block*bucket, bucket-contiguous staging)
//       -> dst_hist (per-bucket LDS, coalesced cnt) -> scans -> refine
//       (per-bucket LDS cursors, contiguous crec range).  Self loops written
//       at rowp[n]+cnt[n] in scan3 with mean(edge_weight).
//   - 2 dual fp32 GEMMs, 8x8 register tiling; xl stored fp16, xr fp32.
//   - Aggregation: one wave per node; half2 gather per edge; DPP 16-lane
//     logit sum; depth-4 rolling prefetch pipeline.
//   - Staging arrays aliased into h1 region (dead until agg1).
// ---------------------------------------------------------------------------

__global__ __launch_bounds__(256) void bucket_hist_sum(
    const int* __restrict__ dst, const float* __restrict__ ew,
    int* __restrict__ bcnt, float* __restrict__ sumbuf, int E) {
    __shared__ int h[256];
    h[threadIdx.x] = 0;
    __syncthreads();
    float s = 0.f;
    for (int i = blockIdx.x * blockDim.x + threadIdx.x; i < E; i += gridDim.x * blockDim.x) {
        atomicAdd(&h[dst[i] >> 8], 1);
        s += ew[i];
    }
#pragma unroll
    for (int off = 1; off <= 32; off <<= 1)
        s += __shfl_xor(s, off, 64);
    if ((threadIdx.x & 63) == 0)
        atomicAdd(sumbuf, s);
    __syncthreads();
    int v = h[threadIdx.x];
    if (v) atomicAdd(&bcnt[threadIdx.x], v);
}

// exclusive scan of bcnt[0..NBK) -> bbase[0..NBK]; bcur = copy of bbase
__global__ void bucket_scan(const int* __restrict__ bcnt, int* __restrict__ bbase,
                            int* __restrict__ bcur, int NBK) {
    __shared__ int sh[256];
    int t = threadIdx.x;
    int v = (t < NBK) ? bcnt[t] : 0;
    sh[t] = v;
    __syncthreads();
    for (int off = 1; off < 256; off <<= 1) {
        int y = 0;
        if (t >= off) y = sh[t - off];
        __syncthreads();
        sh[t] += y;
        __syncthreads();
    }
    int ex = sh[t] - v;
    if (t <= NBK) bbase[t] = ex;     // bbase[NBK] == total == E
    if (t < NBK) bcur[t] = ex;
}

// Partition edges into bucket-contiguous staging.  4096 edges per block.
__global__ __launch_bounds__(256) void partition_kernel(
    const int* __restrict__ src, const int* __restrict__ dst, const float* __restrict__ ew,
    int* __restrict__ bcur, int2* __restrict__ srec, int* __restrict__ sdst, int E) {
    __shared__ int h[256];
    __shared__ int gb[256];
    const int t = threadIdx.x;
    h[t] = 0;
    __syncthreads();
    const int base = blockIdx.x * 4096;
    int d[16], sv[16];
    float wv[16];
#pragma unroll
    for (int j = 0; j < 16; j++) {
        int i = base + t + j * 256;
        if (i < E) {
            d[j] = dst[i];
            sv[j] = src[i];
            wv[j] = ew[i];
            atomicAdd(&h[d[j] >> 8], 1);
        } else {
            d[j] = -1;
        }
    }
    __syncthreads();
    int cntt = h[t];
    if (cntt) gb[t] = atomicAdd(&bcur[t], cntt);
    h[t] = 0;
    __syncthreads();
#pragma unroll
    for (int j = 0; j < 16; j++) {
        if (d[j] >= 0) {
            int b = d[j] >> 8;
            int r = atomicAdd(&h[b], 1);
            int pos = gb[b] + r;
            srec[pos] = make_int2(sv[j], __float_as_int(wv[j]));
            sdst[pos] = d[j];
        }
    }
}

// Per-bucket LDS histogram of exact dst -> cnt (coalesced write, no atomics).
__global__ __launch_bounds__(256) void dst_hist_kernel(
    const int* __restrict__ sdst, const int* __restrict__ bbase,
    int* __restrict__ cnt, int N) {
    __shared__ int h[256];
    const int t = threadIdx.x;
    const int b = blockIdx.x;
    h[t] = 0;
    __syncthreads();
    const int e0 = bbase[b], e1 = bbase[b + 1];
    for (int i = e0 + t; i < e1; i += 256)
        atomicAdd(&h[sdst[i] & 255], 1);
    __syncthreads();
    int node = (b << 8) + t;
    if (node < N) cnt[node] = h[t];
}

__global__ void scan1_kernel(const int* __restrict__ cnt, int* __restrict__ rowp,
                             int* __restrict__ bsum, int N) {
    __shared__ int sh[256];
    int i = blockIdx.x * 256 + threadIdx.x;
    int v = (i < N) ? (cnt[i] + 1) : 0;
    sh[threadIdx.x] = v;
    __syncthreads();
    for (int off = 1; off < 256; off <<= 1) {
        int y = 0;
        if ((int)threadIdx.x >= off) y = sh[threadIdx.x - off];
        __syncthreads();
        sh[threadIdx.x] += y;
        __syncthreads();
    }
    int incl = sh[threadIdx.x];
    if (i < N) rowp[i] = incl - v;
    if (threadIdx.x == 255) bsum[blockIdx.x] = incl;
}

__global__ void scan2_kernel(int* __restrict__ bsum, int nb) {
    __shared__ int sh[256];
    int v = ((int)threadIdx.x < nb) ? bsum[threadIdx.x] : 0;
    sh[threadIdx.x] = v;
    __syncthreads();
    for (int off = 1; off < 256; off <<= 1) {
        int y = 0;
        if ((int)threadIdx.x >= off) y = sh[threadIdx.x - off];
        __syncthreads();
        sh[threadIdx.x] += y;
        __syncthreads();
    }
    int incl = sh[threadIdx.x];
    if ((int)threadIdx.x < nb) bsum[threadIdx.x] = incl - v;
}

// finalize rowp; write self-loop record at rowp[i]+cnt[i].
__global__ void scan3_kernel(int* __restrict__ rowp, const int* __restrict__ bsum,
                             const int* __restrict__ cnt, const float* __restrict__ sumbuf,
                             int2* __restrict__ crec, int N, int E) {
    int i = blockIdx.x * 256 + threadIdx.x;
    if (i < N) {
        int rp = rowp[i] + bsum[blockIdx.x];
        rowp[i] = rp;
        crec[rp + cnt[i]] = make_int2(i, __float_as_int(sumbuf[0] * (1.0f / (float)E)));
    }
    if (i == 0) rowp[N] = E + N;
}

// Per-bucket placement into final CSR slots (LDS cursors from rowp).
__global__ __launch_bounds__(256) void refine_kernel(
    const int2* __restrict__ srec, const int* __restrict__ sdst,
    const int* __restrict__ bbase, const int* __restrict__ rowp,
    int2* __restrict__ crec, int N) {
    __shared__ int cur[256];
    const int t = threadIdx.x;
    const int b = blockIdx.x;
    int node = (b << 8) + t;
    cur[t] = (node < N) ? rowp[node] : 0;
    __syncthreads();
    const int e0 = bbase[b], e1 = bbase[b + 1];
    for (int i = e0 + t; i < e1; i += 256) {
        int2 rec = srec[i];
        int d = sdst[i];
        int pos = atomicAdd(&cur[d & 255], 1);
        crec[pos] = rec;
    }
}

// Yh = half(X @ Wa)  [N x 128 fp16], Yb = X @ Wb  [N x 128 fp32].
__global__ __launch_bounds__(256) void gemm_dual2_kernel(
    const float* __restrict__ X, const float* __restrict__ Wa, const float* __restrict__ Wb,
    __half* __restrict__ Yh, float* __restrict__ Yb, int N) {
    __shared__ float At[32][68];   // [k][row]
    const int tid = threadIdx.x;
    const int rb = blockIdx.x * 64;
    const int tx = tid & 31;
    const int ty = tid >> 5;

    float acc[8][8];
#pragma unroll
    for (int r = 0; r < 8; r++)
#pragma unroll
        for (int c = 0; c < 8; c++) acc[r][c] = 0.f;

    for (int k0 = 0; k0 < 128; k0 += 32) {
        __syncthreads();
        for (int i = tid; i < 512; i += 256) {
            int row = i >> 3;
            int kq = i & 7;
            float4 v = make_float4(0.f, 0.f, 0.f, 0.f);
            if (rb + row < N)
                v = ((const float4*)X)[(size_t)(rb + row) * 32 + (k0 >> 2) + kq];
            At[kq * 4 + 0][row] = v.x;
            At[kq * 4 + 1][row] = v.y;
            At[kq * 4 + 2][row] = v.z;
            At[kq * 4 + 3][row] = v.w;
        }
        __syncthreads();
#pragma unroll
        for (int k = 0; k < 32; k++) {
            float4 a0 = *(const float4*)&At[k][ty * 8];
            float4 a1 = *(const float4*)&At[k][ty * 8 + 4];
            float4 b0 = ((const float4*)(Wa + (size_t)(k0 + k) * 128))[tx];
            float4 b1 = ((const float4*)(Wb + (size_t)(k0 + k) * 128))[tx];
            float ar[8] = {a0.x, a0.y, a0.z, a0.w, a1.x, a1.y, a1.z, a1.w};
            float bc[8] = {b0.x, b0.y, b0.z, b0.w, b1.x, b1.y, b1.z, b1.w};
#pragma unroll
            for (int r = 0; r < 8; r++)
#pragma unroll
                for (int c = 0; c < 8; c++)
                    acc[r][c] = fmaf(ar[r], bc[c], acc[r][c]);
        }
    }

#pragma unroll
    for (int r = 0; r < 8; r++) {
        int row = rb + ty * 8 + r;
        if (row < N) {
            __half2 h01, h23;
            h01.x = __float2half_rn(acc[r][0]); h01.y = __float2half_rn(acc[r][1]);
            h23.x = __float2half_rn(acc[r][2]); h23.y = __float2half_rn(acc[r][3]);
            __half2 hp[2] = {h01, h23};
            ((uint2*)Yh)[(size_t)row * 32 + tx] = *(uint2*)hp;   // 32 uint2/row
            ((float4*)Yb)[(size_t)row * 32 + tx] =
                make_float4(acc[r][4], acc[r][5], acc[r][6], acc[r][7]);
        }
    }
}

// DPP partial-sum step: v += lane-permuted(v) within 16-lane rows. VALU-pipe.
template <int CTRL>
__device__ __forceinline__ float dpp_sum_step(float v) {
    int t = __builtin_amdgcn_update_dpp(0, __float_as_int(v), CTRL, 0xF, 0xF, true);
    return v + __int_as_float(t);
}

// One wave per node. lane l: head h=l>>4, c=l&15, channels j0=32h+2c, j0+1.
__global__ __launch_bounds__(256) void agg_kernel(
    const __half* __restrict__ xlh, const float* __restrict__ xr,
    const int* __restrict__ rowp, const int2* __restrict__ crec,
    const float* __restrict__ We, const float* __restrict__ att, const float* __restrict__ bias,
    float* __restrict__ out, int N, int mode) {
    const int wid = threadIdx.x >> 6;
    const int lane = threadIdx.x & 63;
    const int n = blockIdx.x * 4 + wid;
    if (n >= N) return;
    const int j0 = ((lane >> 4) << 5) + ((lane & 15) << 1);   // 32h + 2c
    const float LOG2E = 1.4426950408889634f;
    const float2 we = *(const float2*)(We + j0);
    float2 at = *(const float2*)(att + j0);
    const float at0 = at.x * LOG2E, at1 = at.y * LOG2E;
    const float2 xrv = *(const float2*)(xr + (size_t)n * 128 + j0);
    float l0 = 0.f, a0 = 0.f, a1 = 0.f;
    const int e0 = __builtin_amdgcn_readfirstlane(rowp[n]);
    const int e1 = __builtin_amdgcn_readfirstlane(rowp[n + 1]);
    const int cnt = e1 - e0;

    auto gather = [&](int s) -> unsigned {
        return *(const unsigned*)(xlh + (size_t)s * 128 + j0);   // half2
    };
    auto process = [&](unsigned xb, float w) {
        float2 xv = __half22float2(*(__half2*)&xb);
        float z0 = xv.x + fmaf(w, we.x, xrv.x);
        float z1 = xv.y + fmaf(w, we.y, xrv.y);
        z0 = fmaxf(z0, 0.f) + 0.2f * fminf(z0, 0.f);   // leaky relu
        z1 = fmaxf(z1, 0.f) + 0.2f * fminf(z1, 0.f);
        float p = fmaf(z1, at1, z0 * at0);
        p = dpp_sum_step<0xB1>(p);    // quad_perm [1,0,3,2]  (xor 1)
        p = dpp_sum_step<0x4E>(p);    // quad_perm [2,3,0,1]  (xor 2)
        p = dpp_sum_step<0x124>(p);   // row_ror:4
        p = dpp_sum_step<0x128>(p);   // row_ror:8
        float q = __builtin_amdgcn_exp2f(p);
        l0 += q;
        a0 = fmaf(q, xv.x, a0);
        a1 = fmaf(q, xv.y, a1);
    };

    if (cnt >= 4) {
        int e = e0;
        int2 r0 = crec[e], r1 = crec[e + 1], r2 = crec[e + 2], r3 = crec[e + 3];
        unsigned b0 = gather(r0.x), b1 = gather(r1.x), b2 = gather(r2.x), b3 = gather(r3.x);
        float w0 = __int_as_float(r0.y), w1 = __int_as_float(r1.y);
        float w2 = __int_as_float(r2.y), w3 = __int_as_float(r3.y);
        e += 4;
        int done = 0;
        while (cnt - done >= 8) {
            int2 s0 = crec[e], s1 = crec[e + 1], s2 = crec[e + 2], s3 = crec[e + 3];
            unsigned n0 = gather(s0.x), n1 = gather(s1.x), n2 = gather(s2.x), n3 = gather(s3.x);
            process(b0, w0); process(b1, w1); process(b2, w2); process(b3, w3);
            b0 = n0; w0 = __int_as_float(s0.y);
            b1 = n1; w1 = __int_as_float(s1.y);
            b2 = n2; w2 = __int_as_float(s2.y);
            b3 = n3; w3 = __int_as_float(s3.y);
            e += 4; done += 4;
        }
        int extra = cnt - done - 4;   // 0..3 unfetched
        unsigned n0 = 0, n1 = 0, n2 = 0;
        float v0 = 0.f, v1 = 0.f, v2 = 0.f;
        if (extra > 0) { int2 r = crec[e];     n0 = gather(r.x); v0 = __int_as_float(r.y); }
        if (extra > 1) { int2 r = crec[e + 1]; n1 = gather(r.x); v1 = __int_as_float(r.y); }
        if (extra > 2) { int2 r = crec[e + 2]; n2 = gather(r.x); v2 = __int_as_float(r.y); }
        process(b0, w0); process(b1, w1); process(b2, w2); process(b3, w3);
        if (extra > 0) process(n0, v0);
        if (extra > 1) process(n1, v1);
        if (extra > 2) process(n2, v2);
    } else {
        for (int e = e0; e < e1; ++e) {
            int2 r = crec[e];
            process(gather(r.x), __int_as_float(r.y));
        }
    }

    float rdenom = 1.0f / (l0 + 1e-16f);
    float r0 = a0 * rdenom;
    float r1 = a1 * rdenom;
    if (mode == 0) {
        float2 bv = *(const float2*)(bias + j0);
        float v0 = r0 + bv.x; v0 = (v0 > 0.f) ? v0 : (__expf(v0) - 1.f);  // ELU
        float v1 = r1 + bv.y; v1 = (v1 > 0.f) ? v1 : (__expf(v1) - 1.f);
        *(float2*)(out + (size_t)n * 128 + j0) = make_float2(v0, v1);
    } else {
        float t0 = r0, t1 = r1;            // mean over 4 heads (lane>>4 groups)
        t0 += __shfl_xor(t0, 16, 64);
        t0 += __shfl_xor(t0, 32, 64);
        t1 += __shfl_xor(t1, 16, 64);
        t1 += __shfl_xor(t1, 32, 64);
        if (lane < 16) {
            int c2 = lane << 1;
            float2 bv = *(const float2*)(bias + c2);
            *(float2*)(out + (size_t)n * 32 + c2) =
                make_float2(0.25f * t0 + bv.x, 0.25f * t1 + bv.y);
        }
    }
}

extern "C" void kernel_launch(void* const* d_in, const int* in_sizes, int n_in,
                              void* d_out, int out_size, void* d_ws, size_t ws_size,
                              hipStream_t stream) {
    const float* x    = (const float*)d_in[0];
    const int*  eidx  = (const int*)d_in[1];
    const float* ew   = (const float*)d_in[2];
    const float* Wl1  = (const float*)d_in[3];
    const float* Wr1  = (const float*)d_in[4];
    const float* We1  = (const float*)d_in[5];
    const float* att1 = (const float*)d_in[6];
    const float* b1   = (const float*)d_in[7];
    const float* Wl2  = (const float*)d_in[8];
    const float* Wr2  = (const float*)d_in[9];
    const float* We2  = (const float*)d_in[10];
    const float* att2 = (const float*)d_in[11];
    const float* b2   = (const float*)d_in[12];

    const int N = in_sizes[0] / 128;
    const int E = in_sizes[1] / 2;
    const int* src = eidx;
    const int* dst = eidx + E;
    const int NBK = (N + 255) >> 8;   // coarse buckets of 256 dst nodes

    char* p = (char*)d_ws;
    auto alloc = [&](size_t bytes) -> void* {
        void* r = (void*)p;
        p += (bytes + 255) & ~(size_t)255;
        return r;
    };
    __half* xlh   = (__half*)alloc((size_t)N * 128 * sizeof(__half));
    float* xr     = (float*)alloc((size_t)N * 128 * sizeof(float));
    float* h1     = (float*)alloc((size_t)N * 128 * sizeof(float));
    int2*  crec   = (int2*)alloc((size_t)(E + N) * sizeof(int2));
    int*   rowp   = (int*)alloc((size_t)(N + 1) * sizeof(int));
    int*   cnt    = (int*)alloc((size_t)N * sizeof(int));
    int*   bcnt   = (int*)alloc(260 * sizeof(int));   // +sumbuf at [256]
    float* sumbuf = (float*)(bcnt + 256);
    int*   bbase  = (int*)alloc(260 * sizeof(int));
    int*   bcur   = (int*)alloc(260 * sizeof(int));
    int*   bsum   = (int*)alloc(256 * sizeof(int));
    // staging aliased into h1 (dead until agg1 writes it; refine finishes first)
    int2*  srec   = (int2*)h1;
    int*   sdst   = (int*)((char*)h1 + (size_t)E * sizeof(int2));

    hipMemsetAsync(bcnt, 0, 260 * sizeof(int), stream);

    bucket_hist_sum<<<1024, 256, 0, stream>>>(dst, ew, bcnt, sumbuf, E);
    bucket_scan<<<1, 256, 0, stream>>>(bcnt, bbase, bcur, NBK);
    partition_kernel<<<(E + 4095) / 4096, 256, 0, stream>>>(src, dst, ew, bcur,
                                                            srec, sdst, E);
    dst_hist_kernel<<<NBK, 256, 0, stream>>>(sdst, bbase, cnt, N);

    int nb = (N + 255) / 256;
    scan1_kernel<<<nb, 256, 0, stream>>>(cnt, rowp, bsum, N);
    scan2_kernel<<<1, 256, 0, stream>>>(bsum, nb);
    scan3_kernel<<<nb, 256, 0, stream>>>(rowp, bsum, cnt, sumbuf, crec, N, E);

    refine_kernel<<<NBK, 256, 0, stream>>>(srec, sdst, bbase, rowp, crec, N);

    // Layer 1
    gemm_dual2_kernel<<<(N + 63) / 64, 256, 0, stream>>>(x, Wl1, Wr1, xlh, xr, N);
    agg_kernel<<<(N + 3) / 4, 256, 0, stream>>>(xlh, xr, rowp, crec,
                                                We1, att1, b1, h1, N, 0);
    // Layer 2
    gemm_dual2_kernel<<<(N + 63) / 64, 256, 0, stream>>>(h1, Wl2, Wr2, xlh, xr, N);
    agg_kernel<<<(N + 3) / 4, 256, 0, stream>>>(xlh, xr, rowp, crec,
                                                We2, att2, b2, (float*)d_out, N, 1);
}